// Round 4
// baseline (1164.691 us; speedup 1.0000x reference)
//
#include <hip/hip_runtime.h>
#include <cstdint>
#include <cstddef>

// Sizes: B=16, T=8, K=4, DIN=9408, H1=1024, F=512, MH=128
#define NB 512

// ---------------- init: zero grid-barrier counters (every replay) ----------------
__global__ void init_kernel(int* bar) {
  if (threadIdx.x < 32) bar[threadIdx.x] = 0;
}

// ---------------- device-scope grid barrier (all NB blocks co-resident) ----------------
__device__ __forceinline__ void gridbar(int* bar, int slot) {
  __syncthreads();
  __threadfence();                      // release: my stores visible device-wide
  if (threadIdx.x == 0) {
    atomicAdd(&bar[slot], 1);           // device-scope by default
    while (__hip_atomic_load(&bar[slot], __ATOMIC_ACQUIRE, __HIP_MEMORY_SCOPE_AGENT) < NB) {
      __builtin_amdgcn_s_sleep(2);
    }
  }
  __syncthreads();
  __threadfence();                      // acquire side for all threads
}

// ---------------- skinny GEMM phase body (M=16, VEC=2, software-pipelined) ----------------
// Stages (optionally scaled) A-chunk to LDS [kk*20+b], streams B rows, writes P[c][16][N].
template<int KC, int UF>
__device__ __forceinline__ void gemm_body(
    float* sh, const float* __restrict__ A, int lda, int iLoc0,
    const float* scales, int sstride,          // scale per b: scales[b*sstride]; nullptr => 1
    const float* __restrict__ B,               // chunk base (row 0 of this chunk)
    int N, int j0,
    float* __restrict__ P, int c)
{
  static_assert(KC % UF == 0, "");
  constexpr int NG = KC / UF;
  static_assert(NG >= 2, "");
  const int tid = threadIdx.x;

  for (int b = 0; b < 16; ++b) {
    float s = scales ? scales[b * sstride] : 1.f;
    const float* Arow = A + (size_t)b * lda + iLoc0;
    for (int kk = tid; kk < KC; kk += 256)
      sh[kk * 20 + b] = s * Arow[kk];
  }
  __syncthreads();

  const float* Brow = B + j0;
  float acc[16][2];
#pragma unroll
  for (int b = 0; b < 16; ++b) { acc[b][0] = 0.f; acc[b][1] = 0.f; }

  float w0[UF][2], w1[UF][2];
  auto loadg = [&](float (&W)[UF][2], int kb) {
#pragma unroll
    for (int u = 0; u < UF; ++u) {
      float2 t2 = *reinterpret_cast<const float2*>(Brow + (size_t)(kb + u) * N);
      W[u][0] = t2.x; W[u][1] = t2.y;
    }
  };
  auto comp = [&](const float (&W)[UF][2], int kb) {
#pragma unroll
    for (int u = 0; u < UF; ++u) {
      int kk = kb + u;
      const float4 a0 = *reinterpret_cast<const float4*>(&sh[kk * 20 + 0]);
      const float4 a1 = *reinterpret_cast<const float4*>(&sh[kk * 20 + 4]);
      const float4 a2 = *reinterpret_cast<const float4*>(&sh[kk * 20 + 8]);
      const float4 a3 = *reinterpret_cast<const float4*>(&sh[kk * 20 + 12]);
      const float av[16] = {a0.x, a0.y, a0.z, a0.w, a1.x, a1.y, a1.z, a1.w,
                            a2.x, a2.y, a2.z, a2.w, a3.x, a3.y, a3.z, a3.w};
#pragma unroll
      for (int b = 0; b < 16; ++b) {
        acc[b][0] = fmaf(av[b], W[u][0], acc[b][0]);
        acc[b][1] = fmaf(av[b], W[u][1], acc[b][1]);
      }
    }
  };

  loadg(w0, 0);
  if constexpr (NG % 2 == 0) {
#pragma unroll 1
    for (int g = 0; g + 2 < NG; g += 2) {
      loadg(w1, (g + 1) * UF);
      comp(w0, g * UF);
      loadg(w0, (g + 2) * UF);
      comp(w1, (g + 1) * UF);
    }
    loadg(w1, (NG - 1) * UF);
    comp(w0, (NG - 2) * UF);
    comp(w1, (NG - 1) * UF);
  } else {
#pragma unroll 1
    for (int g = 0; g + 3 < NG; g += 2) {
      loadg(w1, (g + 1) * UF);
      comp(w0, g * UF);
      loadg(w0, (g + 2) * UF);
      comp(w1, (g + 1) * UF);
    }
    loadg(w1, (NG - 2) * UF);
    comp(w0, (NG - 3) * UF);
    loadg(w0, (NG - 1) * UF);
    comp(w1, (NG - 2) * UF);
    comp(w0, (NG - 1) * UF);
  }

  float* Pb = P + ((size_t)c * 16) * N + j0;
#pragma unroll
  for (int b = 0; b < 16; ++b) {
    *reinterpret_cast<float2*>(Pb) = make_float2(acc[b][0], acc[b][1]);
    Pb += N;
  }
}

// ---------------- reduce phase body ----------------
// 8 slices x CPS chunks; 32 f-cols per block. MODE: 1=z1/t1, 2=base, 3=h (slice-scale), 4=out
template<int CPS, int FTOT, int MODE>
__device__ __forceinline__ void reduce_phase(
    float* sh, const float* __restrict__ P,
    const float* __restrict__ bias, const float* __restrict__ coefs,
    const float* __restrict__ dvec,
    float* __restrict__ o1, float* __restrict__ o2, int blk)
{
  if (blk >= FTOT / 32) return;
  float (*r)[33] = (float(*)[33])sh;
  const int fl = threadIdx.x & 31, s = threadIdx.x >> 5;
  const int f = blk * 32 + fl;

  const float* p = P + (size_t)s * CPS * FTOT + f;
  float sum = 0.f;
#pragma unroll 4
  for (int cc = 0; cc < CPS; ++cc) { sum += *p; p += FTOT; }
  if constexpr (MODE == 3) {
    int b = f >> 10;
    sum *= coefs[b * 32 + s * 4 + 0];   // cW1[b, t=s]
  }
  r[s][fl] = sum;
  __syncthreads();

  if (s == 0) {
    float v = r[0][fl] + r[1][fl] + r[2][fl] + r[3][fl]
            + r[4][fl] + r[5][fl] + r[6][fl] + r[7][fl];
    if constexpr (MODE == 1) {
      float z = v + bias[f & 1023];
      o1[f] = z;
      o2[f] = fmaxf(z, 0.f);
    } else if constexpr (MODE == 2) {
      o1[f] = v + bias[f & 511];
    } else if constexpr (MODE == 3) {
      int b = f >> 10, j = f & 1023;
      float z = v + bias[f];            // bias = z1
#pragma unroll
      for (int t = 0; t < 8; ++t) z = fmaf(coefs[b * 32 + t * 4 + 1], dvec[t * 1024 + j], z);
      o1[f] = fmaxf(z, 0.f);
    } else {
      int b = f >> 9, k = f & 511;
      float z = v + bias[k];            // bias = b2
#pragma unroll
      for (int t = 0; t < 8; ++t) z = fmaf(coefs[b * 32 + t * 4 + 3], dvec[t * 512 + k], z);
      o1[f] = z;
    }
  }
}

// ---------------- the mega-kernel ----------------
__global__ __launch_bounds__(256, 2) void mega_kernel(
    const float* __restrict__ x,
    const float* __restrict__ W1, const float* __restrict__ b1,
    const float* __restrict__ W2, const float* __restrict__ b2,
    const float* __restrict__ dW1, const float* __restrict__ db1,
    const float* __restrict__ dW2, const float* __restrict__ db2,
    const float* __restrict__ mW1, const float* __restrict__ mb1,
    const float* __restrict__ mW2, const float* __restrict__ mb2,
    float* __restrict__ out, float* __restrict__ ws, int* __restrict__ bar)
{
  const int blk = blockIdx.x, tid = threadIdx.x;
  __shared__ float sh[294 * 20];   // 23.5 KB, unioned across phases

  float* xp    = ws + 32;
  float* z1    = xp + 150528;
  float* t1    = z1 + 16384;
  float* base  = t1 + 16384;
  float* coefs = base + 8192;
  float* h     = coefs + 512;
  float* P1    = h + 16384;          // 224*16384
  float* P2    = P1 + 3670016;       // 128*8192
  float* P3    = P2 + 1048576;       // 256*16384
  float* P4    = P3 + 4194304;       // 288*8192

  // ---- P0: pool ----
  for (int tile = blk; tile < 588; tile += NB) {
    int idx = tile * 256 + tid;
    int bc = idx / 3136;
    int rr = idx - bc * 3136;
    int i  = rr / 56;
    int j  = rr - i * 56;
    const float* src = x + ((size_t)bc * 224 + 4 * i) * 224 + 4 * j;
    float s = 0.f;
#pragma unroll
    for (int q = 0; q < 4; ++q) {
      float4 v = *reinterpret_cast<const float4*>(src + q * 224);
      s += v.x + v.y + v.z + v.w;
    }
    xp[idx] = s * 0.0625f;
  }
  gridbar(bar, 0);

  // ---- P1: G1 = xp @ W1 -> P1 (224 chunks KC=42, 2 j-groups) ----
  if (blk < 448) {
    int c = blk >> 1, jg = blk & 1;
    gemm_body<42, 7>(sh, xp, 9408, c * 42, nullptr, 0,
                     W1 + (size_t)(c * 42) * 1024, 1024, (jg * 256 + tid) * 2, P1, c);
  }
  gridbar(bar, 1);

  // ---- P2: R1 -> z1, t1 ----
  reduce_phase<28, 16384, 1>(sh, P1, b1, nullptr, nullptr, z1, t1, blk);
  gridbar(bar, 2);

  // ---- P3: G2 = t1 @ W2 -> P2 (128 chunks KC=8) ----
  if (blk < 128) {
    gemm_body<8, 4>(sh, t1, 1024, blk * 8, nullptr, 0,
                    W2 + (size_t)(blk * 8) * 512, 512, tid * 2, P2, blk);
  }
  gridbar(bar, 3);

  // ---- P4: R2 -> base ----
  reduce_phase<16, 8192, 2>(sh, P2, b2, nullptr, nullptr, base, nullptr, blk);
  gridbar(bar, 4);

  // ---- P5: mcoef -> coefs ----
  if (blk < 16) {
    float* bs = sh;         // 512
    float* ms = sh + 512;   // 128
    for (int i = tid; i < 512; i += 256) bs[i] = base[blk * 512 + i];
    __syncthreads();
    if (tid < 128) {
      float a0 = 0.f, a1 = 0.f, a2 = 0.f, a3 = 0.f;
      for (int k = 0; k < 512; k += 4) {
        a0 = fmaf(bs[k + 0], mW1[(k + 0) * 128 + tid], a0);
        a1 = fmaf(bs[k + 1], mW1[(k + 1) * 128 + tid], a1);
        a2 = fmaf(bs[k + 2], mW1[(k + 2) * 128 + tid], a2);
        a3 = fmaf(bs[k + 3], mW1[(k + 3) * 128 + tid], a3);
      }
      ms[tid] = fmaxf(mb1[tid] + (a0 + a1) + (a2 + a3), 0.f);
    }
    __syncthreads();
    if (tid < 32) {
      float acc = mb2[tid];
      for (int k = 0; k < 128; ++k) acc = fmaf(ms[k], mW2[k * 32 + tid], acc);
      coefs[blk * 32 + tid] = acc;
    }
  }
  gridbar(bar, 5);

  // ---- P6: G3 = xp @ dW1 (unscaled; 256 chunks KC=294, 2 j-groups) ----
  {
    int c = blk >> 1, jg = blk & 1;
    int t = c >> 5, il = (c & 31) * 294;
    gemm_body<294, 14>(sh, xp, 9408, il, nullptr, 0,
                       dW1 + ((size_t)t * 9408 + il) * 1024, 1024,
                       (jg * 256 + tid) * 2, P3, c);
  }
  gridbar(bar, 6);

  // ---- P7: R3 (slice-scaled by cW1) -> h ----
  reduce_phase<32, 16384, 3>(sh, P3, z1, coefs, db1, h, nullptr, blk);
  gridbar(bar, 7);

  // ---- P8: G4 = h @ {dW2 scaled, W2} -> P4 (288 chunks KC=32) ----
  if (blk < 288) {
    const float* Bb; const float* sc; int il;
    if (blk < 256) {
      int t = blk >> 5; il = (blk & 31) * 32;
      Bb = dW2 + ((size_t)t * 1024 + il) * 512;
      sc = coefs + t * 4 + 2;                 // cW2[b,t], stride 32
    } else {
      il = (blk - 256) * 32;
      Bb = W2 + (size_t)il * 512;
      sc = nullptr;
    }
    gemm_body<32, 8>(sh, h, 1024, il, sc, 32, Bb, 512, tid * 2, P4, blk);
  }
  gridbar(bar, 8);

  // ---- P9: R4 -> out ----
  reduce_phase<36, 8192, 4>(sh, P4, b2, coefs, db2, out, nullptr, blk);
}

extern "C" void kernel_launch(void* const* d_in, const int* in_sizes, int n_in,
                              void* d_out, int out_size, void* d_ws, size_t ws_size,
                              hipStream_t stream) {
  const float* x   = (const float*)d_in[0];
  const float* W1  = (const float*)d_in[1];
  const float* b1  = (const float*)d_in[2];
  const float* W2  = (const float*)d_in[3];
  const float* b2  = (const float*)d_in[4];
  const float* dW1 = (const float*)d_in[5];
  const float* db1 = (const float*)d_in[6];
  const float* dW2 = (const float*)d_in[7];
  const float* db2 = (const float*)d_in[8];
  const float* mW1 = (const float*)d_in[9];
  const float* mb1 = (const float*)d_in[10];
  const float* mW2 = (const float*)d_in[11];
  const float* mb2 = (const float*)d_in[12];
  float* out = (float*)d_out;
  float* ws  = (float*)d_ws;
  int*   bar = (int*)d_ws;

  init_kernel<<<1, 64, 0, stream>>>(bar);
  mega_kernel<<<NB, 256, 0, stream>>>(x, W1, b1, W2, b2, dW1, db1, dW2, db2,
                                      mW1, mb1, mW2, mb2, out, ws, bar);
}

// Round 5
// 526.033 us; speedup vs baseline: 2.2141x; 2.2141x over previous
//
#include <hip/hip_runtime.h>
#include <cstdint>
#include <cstddef>

// Sizes: B=16, T=8, K=4, DIN=9408, H1=1024, F=512, MH=128
#define NB 512

// ---------------- init: zero grid-barrier counters (every replay) ----------------
__global__ void init_kernel(int* bar) {
  if (threadIdx.x < 32) bar[threadIdx.x] = 0;
}

// ---------------- device-scope grid barrier (all NB blocks co-resident) ----------------
// Release: ONE threadfence by thread 0 (block stores are already in L2 after
// __syncthreads; the fence writes L2 back device-wide). Arrive + spin use
// RELAXED atomics — no per-poll cache maintenance (an ACQUIRE poll emits an
// L2 invalidate every iteration and self-DoSes the memory system; round-4 bug).
// One acquire-side fence after the count is reached.
__device__ __forceinline__ void gridbar(int* bar, int slot) {
  __syncthreads();
  if (threadIdx.x == 0) {
    __threadfence();                                  // release: L2 writeback
    __hip_atomic_fetch_add(&bar[slot], 1, __ATOMIC_RELAXED, __HIP_MEMORY_SCOPE_AGENT);
    while (__hip_atomic_load(&bar[slot], __ATOMIC_RELAXED, __HIP_MEMORY_SCOPE_AGENT) < NB) {
      __builtin_amdgcn_s_sleep(4);
    }
    __threadfence();                                  // acquire: L2 invalidate (once)
  }
  __syncthreads();
}

// ---------------- skinny GEMM phase body (M=16, VEC=2, software-pipelined) ----------------
// Stages (optionally scaled) A-chunk to LDS [kk*20+b], streams B rows, writes P[c][16][N].
template<int KC, int UF>
__device__ __forceinline__ void gemm_body(
    float* sh, const float* __restrict__ A, int lda, int iLoc0,
    const float* scales, int sstride,          // scale per b: scales[b*sstride]; nullptr => 1
    const float* __restrict__ B,               // chunk base (row 0 of this chunk)
    int N, int j0,
    float* __restrict__ P, int c)
{
  static_assert(KC % UF == 0, "");
  constexpr int NG = KC / UF;
  static_assert(NG >= 2, "");
  const int tid = threadIdx.x;

  for (int b = 0; b < 16; ++b) {
    float s = scales ? scales[b * sstride] : 1.f;
    const float* Arow = A + (size_t)b * lda + iLoc0;
    for (int kk = tid; kk < KC; kk += 256)
      sh[kk * 20 + b] = s * Arow[kk];
  }
  __syncthreads();

  const float* Brow = B + j0;
  float acc[16][2];
#pragma unroll
  for (int b = 0; b < 16; ++b) { acc[b][0] = 0.f; acc[b][1] = 0.f; }

  float w0[UF][2], w1[UF][2];
  auto loadg = [&](float (&W)[UF][2], int kb) {
#pragma unroll
    for (int u = 0; u < UF; ++u) {
      float2 t2 = *reinterpret_cast<const float2*>(Brow + (size_t)(kb + u) * N);
      W[u][0] = t2.x; W[u][1] = t2.y;
    }
  };
  auto comp = [&](const float (&W)[UF][2], int kb) {
#pragma unroll
    for (int u = 0; u < UF; ++u) {
      int kk = kb + u;
      const float4 a0 = *reinterpret_cast<const float4*>(&sh[kk * 20 + 0]);
      const float4 a1 = *reinterpret_cast<const float4*>(&sh[kk * 20 + 4]);
      const float4 a2 = *reinterpret_cast<const float4*>(&sh[kk * 20 + 8]);
      const float4 a3 = *reinterpret_cast<const float4*>(&sh[kk * 20 + 12]);
      const float av[16] = {a0.x, a0.y, a0.z, a0.w, a1.x, a1.y, a1.z, a1.w,
                            a2.x, a2.y, a2.z, a2.w, a3.x, a3.y, a3.z, a3.w};
#pragma unroll
      for (int b = 0; b < 16; ++b) {
        acc[b][0] = fmaf(av[b], W[u][0], acc[b][0]);
        acc[b][1] = fmaf(av[b], W[u][1], acc[b][1]);
      }
    }
  };

  loadg(w0, 0);
  if constexpr (NG % 2 == 0) {
#pragma unroll 1
    for (int g = 0; g + 2 < NG; g += 2) {
      loadg(w1, (g + 1) * UF);
      comp(w0, g * UF);
      loadg(w0, (g + 2) * UF);
      comp(w1, (g + 1) * UF);
    }
    loadg(w1, (NG - 1) * UF);
    comp(w0, (NG - 2) * UF);
    comp(w1, (NG - 1) * UF);
  } else {
#pragma unroll 1
    for (int g = 0; g + 3 < NG; g += 2) {
      loadg(w1, (g + 1) * UF);
      comp(w0, g * UF);
      loadg(w0, (g + 2) * UF);
      comp(w1, (g + 1) * UF);
    }
    loadg(w1, (NG - 2) * UF);
    comp(w0, (NG - 3) * UF);
    loadg(w0, (NG - 1) * UF);
    comp(w1, (NG - 2) * UF);
    comp(w0, (NG - 1) * UF);
  }

  float* Pb = P + ((size_t)c * 16) * N + j0;
#pragma unroll
  for (int b = 0; b < 16; ++b) {
    *reinterpret_cast<float2*>(Pb) = make_float2(acc[b][0], acc[b][1]);
    Pb += N;
  }
}

// ---------------- reduce phase body ----------------
// 8 slices x CPS chunks; 32 f-cols per block. MODE: 1=z1/t1, 2=base, 3=h (slice-scale), 4=out
template<int CPS, int FTOT, int MODE>
__device__ __forceinline__ void reduce_phase(
    float* sh, const float* __restrict__ P,
    const float* __restrict__ bias, const float* __restrict__ coefs,
    const float* __restrict__ dvec,
    float* __restrict__ o1, float* __restrict__ o2, int blk)
{
  if (blk >= FTOT / 32) return;
  float (*r)[33] = (float(*)[33])sh;
  const int fl = threadIdx.x & 31, s = threadIdx.x >> 5;
  const int f = blk * 32 + fl;

  const float* p = P + (size_t)s * CPS * FTOT + f;
  float sum = 0.f;
#pragma unroll 4
  for (int cc = 0; cc < CPS; ++cc) { sum += *p; p += FTOT; }
  if constexpr (MODE == 3) {
    int b = f >> 10;
    sum *= coefs[b * 32 + s * 4 + 0];   // cW1[b, t=s]
  }
  r[s][fl] = sum;
  __syncthreads();

  if (s == 0) {
    float v = r[0][fl] + r[1][fl] + r[2][fl] + r[3][fl]
            + r[4][fl] + r[5][fl] + r[6][fl] + r[7][fl];
    if constexpr (MODE == 1) {
      float z = v + bias[f & 1023];
      o1[f] = z;
      o2[f] = fmaxf(z, 0.f);
    } else if constexpr (MODE == 2) {
      o1[f] = v + bias[f & 511];
    } else if constexpr (MODE == 3) {
      int b = f >> 10, j = f & 1023;
      float z = v + bias[f];            // bias = z1
#pragma unroll
      for (int t = 0; t < 8; ++t) z = fmaf(coefs[b * 32 + t * 4 + 1], dvec[t * 1024 + j], z);
      o1[f] = fmaxf(z, 0.f);
    } else {
      int b = f >> 9, k = f & 511;
      float z = v + bias[k];            // bias = b2
#pragma unroll
      for (int t = 0; t < 8; ++t) z = fmaf(coefs[b * 32 + t * 4 + 3], dvec[t * 512 + k], z);
      o1[f] = z;
    }
  }
}

// ---------------- the mega-kernel ----------------
__global__ __launch_bounds__(256, 2) void mega_kernel(
    const float* __restrict__ x,
    const float* __restrict__ W1, const float* __restrict__ b1,
    const float* __restrict__ W2, const float* __restrict__ b2,
    const float* __restrict__ dW1, const float* __restrict__ db1,
    const float* __restrict__ dW2, const float* __restrict__ db2,
    const float* __restrict__ mW1, const float* __restrict__ mb1,
    const float* __restrict__ mW2, const float* __restrict__ mb2,
    float* __restrict__ out, float* __restrict__ ws, int* __restrict__ bar)
{
  const int blk = blockIdx.x, tid = threadIdx.x;
  __shared__ float sh[294 * 20];   // 23.5 KB, unioned across phases

  float* xp    = ws + 32;
  float* z1    = xp + 150528;
  float* t1    = z1 + 16384;
  float* base  = t1 + 16384;
  float* coefs = base + 8192;
  float* h     = coefs + 512;
  float* P1    = h + 16384;          // 224*16384
  float* P2    = P1 + 3670016;       // 128*8192
  float* P3    = P2 + 1048576;       // 256*16384
  float* P4    = P3 + 4194304;       // 288*8192

  // ---- P0: pool ----
  for (int tile = blk; tile < 588; tile += NB) {
    int idx = tile * 256 + tid;
    int bc = idx / 3136;
    int rr = idx - bc * 3136;
    int i  = rr / 56;
    int j  = rr - i * 56;
    const float* src = x + ((size_t)bc * 224 + 4 * i) * 224 + 4 * j;
    float s = 0.f;
#pragma unroll
    for (int q = 0; q < 4; ++q) {
      float4 v = *reinterpret_cast<const float4*>(src + q * 224);
      s += v.x + v.y + v.z + v.w;
    }
    xp[idx] = s * 0.0625f;
  }
  gridbar(bar, 0);

  // ---- P1: G1 = xp @ W1 -> P1 (224 chunks KC=42, 2 j-groups) ----
  if (blk < 448) {
    int c = blk >> 1, jg = blk & 1;
    gemm_body<42, 7>(sh, xp, 9408, c * 42, nullptr, 0,
                     W1 + (size_t)(c * 42) * 1024, 1024, (jg * 256 + tid) * 2, P1, c);
  }
  gridbar(bar, 1);

  // ---- P2: R1 -> z1, t1 ----
  reduce_phase<28, 16384, 1>(sh, P1, b1, nullptr, nullptr, z1, t1, blk);
  gridbar(bar, 2);

  // ---- P3: G2 = t1 @ W2 -> P2 (128 chunks KC=8) ----
  if (blk < 128) {
    gemm_body<8, 4>(sh, t1, 1024, blk * 8, nullptr, 0,
                    W2 + (size_t)(blk * 8) * 512, 512, tid * 2, P2, blk);
  }
  gridbar(bar, 3);

  // ---- P4: R2 -> base ----
  reduce_phase<16, 8192, 2>(sh, P2, b2, nullptr, nullptr, base, nullptr, blk);
  gridbar(bar, 4);

  // ---- P5: mcoef -> coefs ----
  if (blk < 16) {
    float* bs = sh;         // 512
    float* ms = sh + 512;   // 128
    for (int i = tid; i < 512; i += 256) bs[i] = base[blk * 512 + i];
    __syncthreads();
    if (tid < 128) {
      float a0 = 0.f, a1 = 0.f, a2 = 0.f, a3 = 0.f;
      for (int k = 0; k < 512; k += 4) {
        a0 = fmaf(bs[k + 0], mW1[(k + 0) * 128 + tid], a0);
        a1 = fmaf(bs[k + 1], mW1[(k + 1) * 128 + tid], a1);
        a2 = fmaf(bs[k + 2], mW1[(k + 2) * 128 + tid], a2);
        a3 = fmaf(bs[k + 3], mW1[(k + 3) * 128 + tid], a3);
      }
      ms[tid] = fmaxf(mb1[tid] + (a0 + a1) + (a2 + a3), 0.f);
    }
    __syncthreads();
    if (tid < 32) {
      float acc = mb2[tid];
      for (int k = 0; k < 128; ++k) acc = fmaf(ms[k], mW2[k * 32 + tid], acc);
      coefs[blk * 32 + tid] = acc;
    }
  }
  gridbar(bar, 5);

  // ---- P6: G3 = xp @ dW1 (unscaled; 256 chunks KC=294, 2 j-groups) ----
  {
    int c = blk >> 1, jg = blk & 1;
    int t = c >> 5, il = (c & 31) * 294;
    gemm_body<294, 14>(sh, xp, 9408, il, nullptr, 0,
                       dW1 + ((size_t)t * 9408 + il) * 1024, 1024,
                       (jg * 256 + tid) * 2, P3, c);
  }
  gridbar(bar, 6);

  // ---- P7: R3 (slice-scaled by cW1) -> h ----
  reduce_phase<32, 16384, 3>(sh, P3, z1, coefs, db1, h, nullptr, blk);
  gridbar(bar, 7);

  // ---- P8: G4 = h @ {dW2 scaled, W2} -> P4 (288 chunks KC=32) ----
  if (blk < 288) {
    const float* Bb; const float* sc; int il;
    if (blk < 256) {
      int t = blk >> 5; il = (blk & 31) * 32;
      Bb = dW2 + ((size_t)t * 1024 + il) * 512;
      sc = coefs + t * 4 + 2;                 // cW2[b,t], stride 32
    } else {
      il = (blk - 256) * 32;
      Bb = W2 + (size_t)il * 512;
      sc = nullptr;
    }
    gemm_body<32, 8>(sh, h, 1024, il, sc, 32, Bb, 512, tid * 2, P4, blk);
  }
  gridbar(bar, 8);

  // ---- P9: R4 -> out ----
  reduce_phase<36, 8192, 4>(sh, P4, b2, coefs, db2, out, nullptr, blk);
}

extern "C" void kernel_launch(void* const* d_in, const int* in_sizes, int n_in,
                              void* d_out, int out_size, void* d_ws, size_t ws_size,
                              hipStream_t stream) {
  const float* x   = (const float*)d_in[0];
  const float* W1  = (const float*)d_in[1];
  const float* b1  = (const float*)d_in[2];
  const float* W2  = (const float*)d_in[3];
  const float* b2  = (const float*)d_in[4];
  const float* dW1 = (const float*)d_in[5];
  const float* db1 = (const float*)d_in[6];
  const float* dW2 = (const float*)d_in[7];
  const float* db2 = (const float*)d_in[8];
  const float* mW1 = (const float*)d_in[9];
  const float* mb1 = (const float*)d_in[10];
  const float* mW2 = (const float*)d_in[11];
  const float* mb2 = (const float*)d_in[12];
  float* out = (float*)d_out;
  float* ws  = (float*)d_ws;
  int*   bar = (int*)d_ws;

  init_kernel<<<1, 64, 0, stream>>>(bar);
  mega_kernel<<<NB, 256, 0, stream>>>(x, W1, b1, W2, b2, dW1, db1, dW2, db2,
                                      mW1, mb1, mW2, mb2, out, ws, bar);
}